// Round 5
// baseline (396.176 us; speedup 1.0000x reference)
//
#include <hip/hip_runtime.h>

#define H 128

typedef __attribute__((ext_vector_type(8))) short bf16x8;
typedef __attribute__((ext_vector_type(4))) float f32x4;

__device__ __forceinline__ unsigned short f2bf(float f) {
    unsigned u = __float_as_uint(f);
    u += 0x7FFFu + ((u >> 16) & 1u);
    return (unsigned short)(u >> 16);
}
__device__ __forceinline__ float bflo(unsigned v) { return __uint_as_float(v << 16); }
__device__ __forceinline__ float bfhi(unsigned v) { return __uint_as_float(v & 0xFFFF0000u); }

// ---- CSR build via 2-level bucket sort ----------------------------------
__global__ void __launch_bounds__(256) k_bhist(const int* __restrict__ ei,
                                               int* __restrict__ bhist, int E) {
    __shared__ int h[512];
    int t = threadIdx.x;
    h[t] = 0; h[t + 256] = 0;
    __syncthreads();
    int stride = gridDim.x * 256;
    for (int e = blockIdx.x * 256 + t; e < E; e += stride)
        atomicAdd(&h[ei[E + e] >> 8], 1);
    __syncthreads();
    for (int u = t; u < 512; u += 256) {
        int v = h[u];
        if (v) atomicAdd(&bhist[u], v);
    }
}

__global__ void k_bscan(const int* __restrict__ bhist, int* __restrict__ bbase,
                        int* __restrict__ gcur) {
    __shared__ int sh[512];
    int t = threadIdx.x;
    int v = bhist[t];
    sh[t] = v;
    __syncthreads();
    for (int off = 1; off < 512; off <<= 1) {
        int u = (t >= off) ? sh[t - off] : 0;
        __syncthreads();
        sh[t] += u;
        __syncthreads();
    }
    int ex = sh[t] - v;
    bbase[t] = ex;
    gcur[t] = ex;
    if (t == 511) bbase[512] = sh[t];
}

__global__ void __launch_bounds__(256) k_scatter(const int* __restrict__ ei,
        int* __restrict__ gcur, int2* __restrict__ tmp_sd, int E) {
    __shared__ int hist[512], base[512], fill[512];
    int blk = blockIdx.x, t = threadIdx.x;
    int chunk = (E + gridDim.x - 1) / gridDim.x;
    int c0 = blk * chunk;
    int c1 = c0 + chunk; if (c1 > E) c1 = E;
    hist[t] = 0; hist[t + 256] = 0;
    __syncthreads();
    for (int e = c0 + t; e < c1; e += 256)
        atomicAdd(&hist[ei[E + e] >> 8], 1);
    __syncthreads();
    for (int u = t; u < 512; u += 256) {
        int h = hist[u];
        base[u] = h ? atomicAdd(&gcur[u], h) : 0;
        fill[u] = 0;
    }
    __syncthreads();
    for (int e = c0 + t; e < c1; e += 256) {
        int d = ei[E + e], s = ei[e];
        int bb = d >> 8;
        int p = base[bb] + atomicAdd(&fill[bb], 1);
        tmp_sd[p] = make_int2(s, d);
    }
}

__global__ void __launch_bounds__(256) k_csrA(const int2* __restrict__ tmp_sd,
        const int* __restrict__ bbase, int* __restrict__ rp,
        float* __restrict__ dinv, float* __restrict__ invdeg, int N, int E) {
    __shared__ int cnt[256];
    __shared__ int sh[256];
    int b = blockIdx.x, t = threadIdx.x;
    int e0 = bbase[b], e1 = bbase[b + 1];
    cnt[t] = 0;
    __syncthreads();
    for (int e = e0 + t; e < e1; e += 256)
        atomicAdd(&cnt[tmp_sd[e].y & 255], 1);
    __syncthreads();
    int v = cnt[t];
    sh[t] = v;
    __syncthreads();
    for (int off = 1; off < 256; off <<= 1) {
        int u = (t >= off) ? sh[t - off] : 0;
        __syncthreads();
        sh[t] += u;
        __syncthreads();
    }
    int gid = (b << 8) + t;
    if (gid < N) {
        rp[gid] = e0 + sh[t] - v;
        float dg = (float)(v + 1);
        dinv[gid] = rsqrtf(dg);
        invdeg[gid] = 1.0f / dg;
    }
    if (b == 0 && t == 0) rp[N] = E;
}

__global__ void __launch_bounds__(256) k_csrB(const int2* __restrict__ tmp_sd,
        const int* __restrict__ bbase, const int* __restrict__ rp,
        const float* __restrict__ dinv, int* __restrict__ csrc,
        float* __restrict__ cw, int N) {
    __shared__ int fill[256];
    __shared__ float ld[256];
    int b = blockIdx.x, t = threadIdx.x;
    int e0 = bbase[b], e1 = bbase[b + 1];
    int gid = (b << 8) + t;
    fill[t] = (gid < N) ? rp[gid] : 0;
    ld[t] = (gid < N) ? dinv[gid] : 0.0f;
    __syncthreads();
    for (int e = e0 + t; e < e1; e += 256) {
        int2 sd = tmp_sd[e];
        int l = sd.y & 255;
        int p = atomicAdd(&fill[l], 1);
        csrc[p] = sd.x;
        cw[p] = dinv[sd.x] * ld[l];
    }
}

// ---- dtype prep ---------------------------------------------------------
__global__ void k_xbf(const float* __restrict__ x, unsigned* __restrict__ xb, int n2) {
    int i = blockIdx.x * blockDim.x + threadIdx.x;
    if (i < n2) {
        float2 v = ((const float2*)x)[i];
        xb[i] = (unsigned)f2bf(v.x) | ((unsigned)f2bf(v.y) << 16);
    }
}

// merged weight prep (unchanged from R4)
__global__ void k_wprep(const float* __restrict__ W, const float* __restrict__ b,
                        const float* __restrict__ r3w, const float* __restrict__ r3b,
                        const float* __restrict__ r2w, const float* __restrict__ r2b,
                        unsigned short* __restrict__ Wt, unsigned short* __restrict__ WRb,
                        float* __restrict__ bias2) {
    int idx = blockIdx.x * blockDim.x + threadIdx.x;
    if (idx < 114688) {
        int k = idx >> 14;
        int f = (idx >> 7) & 127;
        int h = idx & 127;
        Wt[(k << 14) + (h << 7) + f] = f2bf(W[idx]);
        return;
    }
    int idx2 = idx - 114688;
    if (idx2 < 14336) {
        int j = idx2 & 7;
        int lane = (idx2 >> 3) & 63;
        int kk = (idx2 >> 9) & 3;
        int k = idx2 >> 11;
        int c = lane & 15;
        int off = ((lane >> 4) << 3) + j;
        int f = kk * 32 + (off >> 1) + ((off & 1) << 4);
        int ck = (k < 5) ? 3 : 2;
        float s = 0.0f;
        if (c < ck) {
            const float* R = (k < 5) ? (r3w + (size_t)(k * 3 + c) * H)
                                     : (r2w + (size_t)((k - 5) * 2 + c) * H);
            const float* Wk = W + (k << 14) + (f << 7);
            for (int h = 0; h < H; ++h) s += Wk[h] * R[h];
        }
        WRb[idx2] = f2bf(s);
    } else if (idx2 < 14336 + 32) {
        int c32 = idx2 - 14336;
        int k = c32 >> 2, c = c32 & 3;
        int ck = (k < 5) ? 3 : 2;
        float t = 0.0f;
        if (c < ck) {
            const float* R = (k < 5) ? (r3w + (size_t)(k * 3 + c) * H)
                                     : (r2w + (size_t)((k - 5) * 2 + c) * H);
            const float* bk = b + k * H;
            for (int h = 0; h < H; ++h) t += bk[h] * R[h];
            t += (k < 5) ? r3b[k * 3 + c] : r2b[(k - 5) * 2 + c];
        }
        bias2[c32] = t;
    }
}

// ---- aggregation 1: px = P_hat @ x --------------------------------------
__global__ void __launch_bounds__(256) k_px(const unsigned* __restrict__ xb,
        const int* __restrict__ rp, const int* __restrict__ csrc,
        const float* __restrict__ cw, const float* __restrict__ invdeg,
        unsigned* __restrict__ pxb, int N) {
    int lane = threadIdx.x & 63;
    int wv = threadIdx.x >> 6;
    int i = blockIdx.x * 4 + wv;
    if (i >= N) return;
    int grp = lane >> 4, sub = lane & 15;
    int s = rp[i], e = rp[i + 1];
    float acc[8] = {0.f, 0.f, 0.f, 0.f, 0.f, 0.f, 0.f, 0.f};
    for (int base = s; base < e; base += 64) {
        int el = base + lane;
        bool ok = el < e;
        int j_l = ok ? csrc[el] : 0;
        float w_l = ok ? cw[el] : 0.0f;
        int cnt = e - base; if (cnt > 64) cnt = 64;
        for (int t = 0; t < cnt; t += 4) {
            int idx = t + grp;
            int jj = __shfl(j_l, idx);
            float ww = __shfl(w_l, idx);
            const uint4 v = *(const uint4*)(xb + (size_t)jj * 64 + sub * 4);
            acc[0] += ww * bflo(v.x); acc[1] += ww * bfhi(v.x);
            acc[2] += ww * bflo(v.y); acc[3] += ww * bfhi(v.y);
            acc[4] += ww * bflo(v.z); acc[5] += ww * bfhi(v.z);
            acc[6] += ww * bflo(v.w); acc[7] += ww * bfhi(v.w);
        }
    }
#pragma unroll
    for (int r = 0; r < 8; ++r) {
        acc[r] += __shfl_xor(acc[r], 16);
        acc[r] += __shfl_xor(acc[r], 32);
    }
    if (grp == 0) {
        const uint4 v = *(const uint4*)(xb + (size_t)i * 64 + sub * 4);
        float id = invdeg[i];
        uint4 o;
        o.x = (unsigned)f2bf(acc[0] + id * bflo(v.x)) | ((unsigned)f2bf(acc[1] + id * bfhi(v.x)) << 16);
        o.y = (unsigned)f2bf(acc[2] + id * bflo(v.y)) | ((unsigned)f2bf(acc[3] + id * bfhi(v.y)) << 16);
        o.z = (unsigned)f2bf(acc[4] + id * bflo(v.z)) | ((unsigned)f2bf(acc[5] + id * bfhi(v.z)) << 16);
        o.w = (unsigned)f2bf(acc[6] + id * bflo(v.w)) | ((unsigned)f2bf(acc[7] + id * bfhi(v.w)) << 16);
        *(uint4*)(pxb + (size_t)i * 64 + sub * 4) = o;
    }
}

// ---- GEMM: u = (relu(px@Wk + bk)) @ WR_k --------------------------------
// 28-stage software pipeline (7 branches x 4 col-groups); B-frags double-
// buffered in registers so next stage's 8 global loads stay in flight under
// current stage's 16 MFMAs (vmcnt never drains to 0). Barrier-free: h1
// transpose through wave-private LDS. 4 waves/block, 32 rows/wave.
__global__ void __launch_bounds__(256, 3) k_gemm(const unsigned short* __restrict__ pxb,
        const unsigned short* __restrict__ Wt, const float* __restrict__ gb,
        const unsigned short* __restrict__ WRb, float* __restrict__ uall, int N) {
    __shared__ __align__(16) unsigned h1w[4][2560];   // per-wave 10 KB, stride-20 regions
    int wv = threadIdx.x >> 6;
    int lane = threadIdx.x & 63;
    int quad = lane >> 4, l16 = lane & 15;
    int row0 = blockIdx.x * 128 + wv * 32;

    bf16x8 af[2][4];
#pragma unroll
    for (int rb = 0; rb < 2; ++rb) {
        int r = row0 + rb * 16 + l16;
        if (r >= N) r = N - 1;
#pragma unroll
        for (int kk = 0; kk < 4; ++kk)
            af[rb][kk] = *(const bf16x8*)(pxb + (size_t)r * H + kk * 32 + quad * 8);
    }
    unsigned* wl = &h1w[wv][0];

    const unsigned short* bp = Wt + (size_t)l16 * H + quad * 8;
    bf16x8 bbuf[2][8];
#pragma unroll
    for (int kk = 0; kk < 4; ++kk)
#pragma unroll
        for (int cb = 0; cb < 2; ++cb)
            bbuf[0][kk * 2 + cb] = *(const bf16x8*)(bp + (size_t)cb * 16 * H + kk * 32);

#pragma unroll
    for (int s = 0; s < 28; ++s) {
        const int k = s >> 2, p = s & 3;
        bf16x8* cur = bbuf[s & 1];
        bf16x8* nxt = bbuf[(s & 1) ^ 1];
        if (s + 1 < 28) {
            const int k2 = (s + 1) >> 2, p2 = (s + 1) & 3;
            const unsigned short* bp2 = bp + (k2 << 14) + (size_t)(p2 * 32) * H;
#pragma unroll
            for (int kk = 0; kk < 4; ++kk)
#pragma unroll
                for (int cb = 0; cb < 2; ++cb)
                    nxt[kk * 2 + cb] = *(const bf16x8*)(bp2 + (size_t)cb * 16 * H + kk * 32);
        }
        float bi0 = gb[k * H + 32 * p + l16];
        float bi1 = gb[k * H + 32 * p + 16 + l16];
        f32x4 cacc[2][2] = {};
#pragma unroll
        for (int kk = 0; kk < 4; ++kk)
#pragma unroll
            for (int rb = 0; rb < 2; ++rb) {
                cacc[rb][0] = __builtin_amdgcn_mfma_f32_16x16x32_bf16(af[rb][kk], cur[kk * 2 + 0], cacc[rb][0], 0, 0, 0);
                cacc[rb][1] = __builtin_amdgcn_mfma_f32_16x16x32_bf16(af[rb][kk], cur[kk * 2 + 1], cacc[rb][1], 0, 0, 0);
            }
#pragma unroll
        for (int rb = 0; rb < 2; ++rb)
#pragma unroll
            for (int r = 0; r < 4; ++r) {
                float lo = fmaxf(cacc[rb][0][r] + bi0, 0.0f);
                float hi = fmaxf(cacc[rb][1][r] + bi1, 0.0f);
                unsigned pk = (unsigned)f2bf(lo) | ((unsigned)f2bf(hi) << 16);
                wl[(p * 32 + rb * 16 + quad * 4 + r) * 20 + l16] = pk;
            }
        if (p == 3) {
            f32x4 u0 = {}, u1 = {};
#pragma unroll
            for (int kk = 0; kk < 4; ++kk) {
                bf16x8 a0 = *(const bf16x8*)(wl + (kk * 32 + l16) * 20 + quad * 4);
                bf16x8 a1 = *(const bf16x8*)(wl + (kk * 32 + 16 + l16) * 20 + quad * 4);
                bf16x8 bw = *(const bf16x8*)(WRb + (size_t)((k * 4 + kk) * 64 + lane) * 8);
                u0 = __builtin_amdgcn_mfma_f32_16x16x32_bf16(a0, bw, u0, 0, 0, 0);
                u1 = __builtin_amdgcn_mfma_f32_16x16x32_bf16(a1, bw, u1, 0, 0, 0);
            }
            if (l16 < 4) {
#pragma unroll
                for (int r = 0; r < 4; ++r) {
                    int ra = row0 + quad * 4 + r;
                    int rb2 = ra + 16;
                    if (ra < N) uall[(size_t)ra * 32 + k * 4 + l16] = u0[r];
                    if (rb2 < N) uall[(size_t)rb2 * 32 + k * 4 + l16] = u1[r];
                }
            }
        }
    }
}

// ---- aggregation 2 + softmax -------------------------------------------
__global__ void __launch_bounds__(256) k_out(const float* __restrict__ uall,
        const int* __restrict__ rp, const int* __restrict__ csrc,
        const float* __restrict__ cw, const float* __restrict__ invdeg,
        const float* __restrict__ bias2, float* __restrict__ out, int N) {
    int lane = threadIdx.x & 63;
    int wv = threadIdx.x >> 6;
    int i = blockIdx.x * 4 + wv;
    if (i >= N) return;
    int grp = lane >> 3, sub = lane & 7;
    int s = rp[i], e = rp[i + 1];
    float a0 = 0.f, a1 = 0.f, a2 = 0.f, a3 = 0.f;
    for (int base = s; base < e; base += 64) {
        int el = base + lane;
        bool ok = el < e;
        int j_l = ok ? csrc[el] : 0;
        float w_l = ok ? cw[el] : 0.0f;
        int cnt = e - base; if (cnt > 64) cnt = 64;
        for (int t = 0; t < cnt; t += 8) {
            int idx = t + grp;
            int jj = __shfl(j_l, idx);
            float ww = __shfl(w_l, idx);
            const float4 v = *(const float4*)(uall + (size_t)jj * 32 + sub * 4);
            a0 += ww * v.x; a1 += ww * v.y; a2 += ww * v.z; a3 += ww * v.w;
        }
    }
#pragma unroll
    for (int m = 8; m <= 32; m <<= 1) {
        a0 += __shfl_xor(a0, m); a1 += __shfl_xor(a1, m);
        a2 += __shfl_xor(a2, m); a3 += __shfl_xor(a3, m);
    }
    if (grp == 0 && sub < 7) {
        int b = sub;
        const float4 v = *(const float4*)(uall + (size_t)i * 32 + b * 4);
        float id = invdeg[i];
        float v0 = a0 + id * v.x + bias2[b * 4 + 0];
        float v1 = a1 + id * v.y + bias2[b * 4 + 1];
        float v2 = a2 + id * v.z + bias2[b * 4 + 2];
        int ck = (b < 5) ? 3 : 2;
        float mx = fmaxf(v0, v1);
        if (ck == 3) mx = fmaxf(mx, v2);
        float e0 = __expf(v0 - mx), e1 = __expf(v1 - mx);
        float e2 = (ck == 3) ? __expf(v2 - mx) : 0.0f;
        float inv = 1.0f / (e0 + e1 + e2);
        size_t basek = (b < 5) ? (size_t)b * 3 * N + (size_t)i * 3
                               : (size_t)15 * N + (size_t)(b - 5) * 2 * N + (size_t)i * 2;
        out[basek + 0] = e0 * inv;
        out[basek + 1] = e1 * inv;
        if (ck == 3) out[basek + 2] = e2 * inv;
    }
}

// ---- launch -------------------------------------------------------------
extern "C" void kernel_launch(void* const* d_in, const int* in_sizes, int n_in,
                              void* d_out, int out_size, void* d_ws, size_t ws_size,
                              hipStream_t stream) {
    (void)n_in; (void)out_size; (void)ws_size;
    const float* x   = (const float*)d_in[0];
    const int*   ei  = (const int*)d_in[1];
    const float* gw  = (const float*)d_in[2];
    const float* gb  = (const float*)d_in[3];
    const float* r3w = (const float*)d_in[4];
    const float* r3b = (const float*)d_in[5];
    const float* r2w = (const float*)d_in[6];
    const float* r2b = (const float*)d_in[7];
    float* out = (float*)d_out;
    int N = in_sizes[0] / H;   // 100000
    int E = in_sizes[1] / 2;   // 1600000
    int NB = (N + 255) >> 8;   // 391 buckets

    char* p = (char*)d_ws;
    auto alloc = [&](size_t bytes) {
        char* q = p;
        p += (bytes + 255) & ~(size_t)255;
        return q;
    };
    unsigned*       xb     = (unsigned*)alloc((size_t)N * 64 * 4);
    unsigned*       pxb    = (unsigned*)alloc((size_t)N * 64 * 4);
    unsigned short* Wt     = (unsigned short*)alloc((size_t)7 * 16384 * 2);
    unsigned short* WRb    = (unsigned short*)alloc((size_t)14336 * 2);
    float*          bias2  = (float*)alloc(32 * 4);
    int*            bhist  = (int*)alloc(512 * 4);
    int*            bbase  = (int*)alloc(513 * 4);
    int*            gcur   = (int*)alloc(512 * 4);
    int2*           tmp_sd = (int2*)alloc((size_t)E * 8);
    int*            rp     = (int*)alloc((size_t)(N + 1) * 4);
    float*          dinv   = (float*)alloc((size_t)N * 4);
    float*          invdeg = (float*)alloc((size_t)N * 4);
    int*            csrc   = (int*)alloc((size_t)E * 4);
    float*          cw     = (float*)alloc((size_t)E * 4);
    float*          uall   = (float*)alloc((size_t)N * 32 * 4);

    hipMemsetAsync(bhist, 0, 512 * 4, stream);
    k_bhist<<<256, 256, 0, stream>>>(ei, bhist, E);
    k_bscan<<<1, 512, 0, stream>>>(bhist, bbase, gcur);
    k_scatter<<<256, 256, 0, stream>>>(ei, gcur, tmp_sd, E);
    k_csrA<<<NB, 256, 0, stream>>>(tmp_sd, bbase, rp, dinv, invdeg, N, E);
    k_csrB<<<NB, 256, 0, stream>>>(tmp_sd, bbase, rp, dinv, csrc, cw, N);
    k_xbf<<<(N * 64 + 255) / 256, 256, 0, stream>>>(x, xb, N * 64);
    k_wprep<<<(114688 + 14368 + 255) / 256, 256, 0, stream>>>(gw, gb, r3w, r3b, r2w, r2b,
                                                              Wt, WRb, bias2);
    k_px<<<(N + 3) / 4, 256, 0, stream>>>(xb, rp, csrc, cw, invdeg, pxb, N);
    k_gemm<<<(N + 127) / 128, 256, 0, stream>>>((const unsigned short*)pxb, Wt, gb, WRb, uall, N);
    k_out<<<(N + 3) / 4, 256, 0, stream>>>(uall, rp, csrc, cw, invdeg, bias2, out, N);
}

// Round 6
// 329.285 us; speedup vs baseline: 1.2031x; 1.2031x over previous
//
#include <hip/hip_runtime.h>

#define H 128

typedef __attribute__((ext_vector_type(8))) short bf16x8;
typedef __attribute__((ext_vector_type(4))) float f32x4;

__device__ __forceinline__ unsigned short f2bf(float f) {
    unsigned u = __float_as_uint(f);
    u += 0x7FFFu + ((u >> 16) & 1u);
    return (unsigned short)(u >> 16);
}
__device__ __forceinline__ float bflo(unsigned v) { return __uint_as_float(v << 16); }
__device__ __forceinline__ float bfhi(unsigned v) { return __uint_as_float(v & 0xFFFF0000u); }

// ---- CSR build via 2-level bucket sort ----------------------------------
__global__ void __launch_bounds__(256) k_bhist(const int* __restrict__ ei,
                                               int* __restrict__ bhist, int E) {
    __shared__ int h[512];
    int t = threadIdx.x;
    h[t] = 0; h[t + 256] = 0;
    __syncthreads();
    int stride = gridDim.x * 256;
    for (int e = blockIdx.x * 256 + t; e < E; e += stride)
        atomicAdd(&h[ei[E + e] >> 8], 1);
    __syncthreads();
    for (int u = t; u < 512; u += 256) {
        int v = h[u];
        if (v) atomicAdd(&bhist[u], v);
    }
}

__global__ void k_bscan(const int* __restrict__ bhist, int* __restrict__ bbase,
                        int* __restrict__ gcur) {
    __shared__ int sh[512];
    int t = threadIdx.x;
    int v = bhist[t];
    sh[t] = v;
    __syncthreads();
    for (int off = 1; off < 512; off <<= 1) {
        int u = (t >= off) ? sh[t - off] : 0;
        __syncthreads();
        sh[t] += u;
        __syncthreads();
    }
    int ex = sh[t] - v;
    bbase[t] = ex;
    gcur[t] = ex;
    if (t == 511) bbase[512] = sh[t];
}

__global__ void __launch_bounds__(256) k_scatter(const int* __restrict__ ei,
        int* __restrict__ gcur, int2* __restrict__ tmp_sd, int E) {
    __shared__ int hist[512], base[512], fill[512];
    int blk = blockIdx.x, t = threadIdx.x;
    int chunk = (E + gridDim.x - 1) / gridDim.x;
    int c0 = blk * chunk;
    int c1 = c0 + chunk; if (c1 > E) c1 = E;
    hist[t] = 0; hist[t + 256] = 0;
    __syncthreads();
    for (int e = c0 + t; e < c1; e += 256)
        atomicAdd(&hist[ei[E + e] >> 8], 1);
    __syncthreads();
    for (int u = t; u < 512; u += 256) {
        int h = hist[u];
        base[u] = h ? atomicAdd(&gcur[u], h) : 0;
        fill[u] = 0;
    }
    __syncthreads();
    for (int e = c0 + t; e < c1; e += 256) {
        int d = ei[E + e], s = ei[e];
        int bb = d >> 8;
        int p = base[bb] + atomicAdd(&fill[bb], 1);
        tmp_sd[p] = make_int2(s, d);
    }
}

__global__ void __launch_bounds__(256) k_csrA(const int2* __restrict__ tmp_sd,
        const int* __restrict__ bbase, int* __restrict__ rp,
        float* __restrict__ dinv, float* __restrict__ invdeg, int N, int E) {
    __shared__ int cnt[256];
    __shared__ int sh[256];
    int b = blockIdx.x, t = threadIdx.x;
    int e0 = bbase[b], e1 = bbase[b + 1];
    cnt[t] = 0;
    __syncthreads();
    for (int e = e0 + t; e < e1; e += 256)
        atomicAdd(&cnt[tmp_sd[e].y & 255], 1);
    __syncthreads();
    int v = cnt[t];
    sh[t] = v;
    __syncthreads();
    for (int off = 1; off < 256; off <<= 1) {
        int u = (t >= off) ? sh[t - off] : 0;
        __syncthreads();
        sh[t] += u;
        __syncthreads();
    }
    int gid = (b << 8) + t;
    if (gid < N) {
        rp[gid] = e0 + sh[t] - v;
        float dg = (float)(v + 1);
        dinv[gid] = rsqrtf(dg);
        invdeg[gid] = 1.0f / dg;
    }
    if (b == 0 && t == 0) rp[N] = E;
}

__global__ void __launch_bounds__(256) k_csrB(const int2* __restrict__ tmp_sd,
        const int* __restrict__ bbase, const int* __restrict__ rp,
        const float* __restrict__ dinv, int* __restrict__ csrc,
        float* __restrict__ cw, int N) {
    __shared__ int fill[256];
    __shared__ float ld[256];
    int b = blockIdx.x, t = threadIdx.x;
    int e0 = bbase[b], e1 = bbase[b + 1];
    int gid = (b << 8) + t;
    fill[t] = (gid < N) ? rp[gid] : 0;
    ld[t] = (gid < N) ? dinv[gid] : 0.0f;
    __syncthreads();
    for (int e = e0 + t; e < e1; e += 256) {
        int2 sd = tmp_sd[e];
        int l = sd.y & 255;
        int p = atomicAdd(&fill[l], 1);
        csrc[p] = sd.x;
        cw[p] = dinv[sd.x] * ld[l];
    }
}

// ---- dtype prep ---------------------------------------------------------
__global__ void k_xbf(const float* __restrict__ x, unsigned* __restrict__ xb, int n2) {
    int i = blockIdx.x * blockDim.x + threadIdx.x;
    if (i < n2) {
        float2 v = ((const float2*)x)[i];
        xb[i] = (unsigned)f2bf(v.x) | ((unsigned)f2bf(v.y) << 16);
    }
}

// merged weight prep (unchanged)
__global__ void k_wprep(const float* __restrict__ W, const float* __restrict__ b,
                        const float* __restrict__ r3w, const float* __restrict__ r3b,
                        const float* __restrict__ r2w, const float* __restrict__ r2b,
                        unsigned short* __restrict__ Wt, unsigned short* __restrict__ WRb,
                        float* __restrict__ bias2) {
    int idx = blockIdx.x * blockDim.x + threadIdx.x;
    if (idx < 114688) {
        int k = idx >> 14;
        int f = (idx >> 7) & 127;
        int h = idx & 127;
        Wt[(k << 14) + (h << 7) + f] = f2bf(W[idx]);
        return;
    }
    int idx2 = idx - 114688;
    if (idx2 < 14336) {
        int j = idx2 & 7;
        int lane = (idx2 >> 3) & 63;
        int kk = (idx2 >> 9) & 3;
        int k = idx2 >> 11;
        int c = lane & 15;
        int off = ((lane >> 4) << 3) + j;
        int f = kk * 32 + (off >> 1) + ((off & 1) << 4);
        int ck = (k < 5) ? 3 : 2;
        float s = 0.0f;
        if (c < ck) {
            const float* R = (k < 5) ? (r3w + (size_t)(k * 3 + c) * H)
                                     : (r2w + (size_t)((k - 5) * 2 + c) * H);
            const float* Wk = W + (k << 14) + (f << 7);
            for (int h = 0; h < H; ++h) s += Wk[h] * R[h];
        }
        WRb[idx2] = f2bf(s);
    } else if (idx2 < 14336 + 32) {
        int c32 = idx2 - 14336;
        int k = c32 >> 2, c = c32 & 3;
        int ck = (k < 5) ? 3 : 2;
        float t = 0.0f;
        if (c < ck) {
            const float* R = (k < 5) ? (r3w + (size_t)(k * 3 + c) * H)
                                     : (r2w + (size_t)((k - 5) * 2 + c) * H);
            const float* bk = b + k * H;
            for (int h = 0; h < H; ++h) t += bk[h] * R[h];
            t += (k < 5) ? r3b[k * 3 + c] : r2b[(k - 5) * 2 + c];
        }
        bias2[c32] = t;
    }
}

// ---- aggregation 1: px = P_hat @ x --------------------------------------
__global__ void __launch_bounds__(256) k_px(const unsigned* __restrict__ xb,
        const int* __restrict__ rp, const int* __restrict__ csrc,
        const float* __restrict__ cw, const float* __restrict__ invdeg,
        unsigned* __restrict__ pxb, int N) {
    int lane = threadIdx.x & 63;
    int wv = threadIdx.x >> 6;
    int i = blockIdx.x * 4 + wv;
    if (i >= N) return;
    int grp = lane >> 4, sub = lane & 15;
    int s = rp[i], e = rp[i + 1];
    float acc[8] = {0.f, 0.f, 0.f, 0.f, 0.f, 0.f, 0.f, 0.f};
    for (int base = s; base < e; base += 64) {
        int el = base + lane;
        bool ok = el < e;
        int j_l = ok ? csrc[el] : 0;
        float w_l = ok ? cw[el] : 0.0f;
        int cnt = e - base; if (cnt > 64) cnt = 64;
        for (int t = 0; t < cnt; t += 4) {
            int idx = t + grp;
            int jj = __shfl(j_l, idx);
            float ww = __shfl(w_l, idx);
            const uint4 v = *(const uint4*)(xb + (size_t)jj * 64 + sub * 4);
            acc[0] += ww * bflo(v.x); acc[1] += ww * bfhi(v.x);
            acc[2] += ww * bflo(v.y); acc[3] += ww * bfhi(v.y);
            acc[4] += ww * bflo(v.z); acc[5] += ww * bfhi(v.z);
            acc[6] += ww * bflo(v.w); acc[7] += ww * bfhi(v.w);
        }
    }
#pragma unroll
    for (int r = 0; r < 8; ++r) {
        acc[r] += __shfl_xor(acc[r], 16);
        acc[r] += __shfl_xor(acc[r], 32);
    }
    if (grp == 0) {
        const uint4 v = *(const uint4*)(xb + (size_t)i * 64 + sub * 4);
        float id = invdeg[i];
        uint4 o;
        o.x = (unsigned)f2bf(acc[0] + id * bflo(v.x)) | ((unsigned)f2bf(acc[1] + id * bfhi(v.x)) << 16);
        o.y = (unsigned)f2bf(acc[2] + id * bflo(v.y)) | ((unsigned)f2bf(acc[3] + id * bfhi(v.y)) << 16);
        o.z = (unsigned)f2bf(acc[4] + id * bflo(v.z)) | ((unsigned)f2bf(acc[5] + id * bfhi(v.z)) << 16);
        o.w = (unsigned)f2bf(acc[6] + id * bflo(v.w)) | ((unsigned)f2bf(acc[7] + id * bfhi(v.w)) << 16);
        *(uint4*)(pxb + (size_t)i * 64 + sub * 4) = o;
    }
}

// ---- GEMM: u = (relu(px@Wk + bk)) @ WR_k --------------------------------
// grid (row-blocks, branch). Per block: stage Wt_k (32KB) into LDS once
// (single barrier), then 4 waves sweep 4x32-row tiles each. B-frags come
// from LDS (short latency, conflict-free at stride 136); A-frags have a
// 2-deep register prefetch across tiles. h1 transpose stays wave-private.
__global__ void __launch_bounds__(256, 2) k_gemm(const unsigned short* __restrict__ pxb,
        const unsigned short* __restrict__ Wt, const float* __restrict__ gb,
        const unsigned short* __restrict__ WRb, float* __restrict__ uall, int N) {
    __shared__ __align__(16) unsigned short Bs[128 * 136];
    __shared__ __align__(16) unsigned h1w[4][2560];
    int k = blockIdx.y;
    int wv = threadIdx.x >> 6;
    int lane = threadIdx.x & 63;
    int quad = lane >> 4, l16 = lane & 15;

    {   // stage Wt_k -> Bs (row stride 136 shorts)
        const unsigned short* src = Wt + (k << 14);
        int t = threadIdx.x;
#pragma unroll
        for (int i = 0; i < 8; ++i) {
            int li = i * 256 + t;
            int f = li >> 4, seg = li & 15;
            *(bf16x8*)(Bs + f * 136 + seg * 8) = *(const bf16x8*)(src + f * 128 + seg * 8);
        }
    }
    __syncthreads();

    unsigned* wl = &h1w[wv][0];
    int rowbase = blockIdx.x * 512 + wv * 32;

    bf16x8 af[2][2][4];
    {
        int rb0 = rowbase;
#pragma unroll
        for (int rb = 0; rb < 2; ++rb) {
            int r = rb0 + rb * 16 + l16;
            if (r >= N) r = N - 1;
#pragma unroll
            for (int kk = 0; kk < 4; ++kk)
                af[0][rb][kk] = *(const bf16x8*)(pxb + (size_t)r * H + kk * 32 + quad * 8);
        }
    }

    float bi[4][2];
#pragma unroll
    for (int p = 0; p < 4; ++p) {
        bi[p][0] = gb[k * H + 32 * p + l16];
        bi[p][1] = gb[k * H + 32 * p + 16 + l16];
    }
    bf16x8 bw[4];
#pragma unroll
    for (int kk = 0; kk < 4; ++kk)
        bw[kk] = *(const bf16x8*)(WRb + (size_t)((k * 4 + kk) * 64 + lane) * 8);

    for (int t = 0; t < 4; ++t) {
        if (t < 3) {
            int rb0 = rowbase + (t + 1) * 128;
#pragma unroll
            for (int rb = 0; rb < 2; ++rb) {
                int r = rb0 + rb * 16 + l16;
                if (r >= N) r = N - 1;
#pragma unroll
                for (int kk = 0; kk < 4; ++kk)
                    af[(t + 1) & 1][rb][kk] = *(const bf16x8*)(pxb + (size_t)r * H + kk * 32 + quad * 8);
            }
        }
        int row0 = rowbase + t * 128;
#pragma unroll
        for (int p = 0; p < 4; ++p) {
            f32x4 cacc[2][2] = {};
#pragma unroll
            for (int kk = 0; kk < 4; ++kk) {
                bf16x8 b0 = *(const bf16x8*)(Bs + (32 * p + l16) * 136 + kk * 32 + quad * 8);
                bf16x8 b1 = *(const bf16x8*)(Bs + (32 * p + 16 + l16) * 136 + kk * 32 + quad * 8);
#pragma unroll
                for (int rb = 0; rb < 2; ++rb) {
                    cacc[rb][0] = __builtin_amdgcn_mfma_f32_16x16x32_bf16(af[t & 1][rb][kk], b0, cacc[rb][0], 0, 0, 0);
                    cacc[rb][1] = __builtin_amdgcn_mfma_f32_16x16x32_bf16(af[t & 1][rb][kk], b1, cacc[rb][1], 0, 0, 0);
                }
            }
#pragma unroll
            for (int rb = 0; rb < 2; ++rb)
#pragma unroll
                for (int r = 0; r < 4; ++r) {
                    float lo = fmaxf(cacc[rb][0][r] + bi[p][0], 0.0f);
                    float hi = fmaxf(cacc[rb][1][r] + bi[p][1], 0.0f);
                    unsigned pk = (unsigned)f2bf(lo) | ((unsigned)f2bf(hi) << 16);
                    wl[(p * 32 + rb * 16 + quad * 4 + r) * 20 + l16] = pk;
                }
        }
        // projection GEMM (K=128 permuted), wave-local, no barrier
        f32x4 u0 = {}, u1 = {};
#pragma unroll
        for (int kk = 0; kk < 4; ++kk) {
            bf16x8 a0 = *(const bf16x8*)(wl + (kk * 32 + l16) * 20 + quad * 4);
            bf16x8 a1 = *(const bf16x8*)(wl + (kk * 32 + 16 + l16) * 20 + quad * 4);
            u0 = __builtin_amdgcn_mfma_f32_16x16x32_bf16(a0, bw[kk], u0, 0, 0, 0);
            u1 = __builtin_amdgcn_mfma_f32_16x16x32_bf16(a1, bw[kk], u1, 0, 0, 0);
        }
        if (l16 < 4) {
#pragma unroll
            for (int r = 0; r < 4; ++r) {
                int ra = row0 + quad * 4 + r;
                int rb2 = ra + 16;
                if (ra < N) uall[(size_t)ra * 32 + k * 4 + l16] = u0[r];
                if (rb2 < N) uall[(size_t)rb2 * 32 + k * 4 + l16] = u1[r];
            }
        }
    }
}

// ---- aggregation 2 + softmax -------------------------------------------
__global__ void __launch_bounds__(256) k_out(const float* __restrict__ uall,
        const int* __restrict__ rp, const int* __restrict__ csrc,
        const float* __restrict__ cw, const float* __restrict__ invdeg,
        const float* __restrict__ bias2, float* __restrict__ out, int N) {
    int lane = threadIdx.x & 63;
    int wv = threadIdx.x >> 6;
    int i = blockIdx.x * 4 + wv;
    if (i >= N) return;
    int grp = lane >> 3, sub = lane & 7;
    int s = rp[i], e = rp[i + 1];
    float a0 = 0.f, a1 = 0.f, a2 = 0.f, a3 = 0.f;
    for (int base = s; base < e; base += 64) {
        int el = base + lane;
        bool ok = el < e;
        int j_l = ok ? csrc[el] : 0;
        float w_l = ok ? cw[el] : 0.0f;
        int cnt = e - base; if (cnt > 64) cnt = 64;
        for (int t = 0; t < cnt; t += 8) {
            int idx = t + grp;
            int jj = __shfl(j_l, idx);
            float ww = __shfl(w_l, idx);
            const float4 v = *(const float4*)(uall + (size_t)jj * 32 + sub * 4);
            a0 += ww * v.x; a1 += ww * v.y; a2 += ww * v.z; a3 += ww * v.w;
        }
    }
#pragma unroll
    for (int m = 8; m <= 32; m <<= 1) {
        a0 += __shfl_xor(a0, m); a1 += __shfl_xor(a1, m);
        a2 += __shfl_xor(a2, m); a3 += __shfl_xor(a3, m);
    }
    if (grp == 0 && sub < 7) {
        int b = sub;
        const float4 v = *(const float4*)(uall + (size_t)i * 32 + b * 4);
        float id = invdeg[i];
        float v0 = a0 + id * v.x + bias2[b * 4 + 0];
        float v1 = a1 + id * v.y + bias2[b * 4 + 1];
        float v2 = a2 + id * v.z + bias2[b * 4 + 2];
        int ck = (b < 5) ? 3 : 2;
        float mx = fmaxf(v0, v1);
        if (ck == 3) mx = fmaxf(mx, v2);
        float e0 = __expf(v0 - mx), e1 = __expf(v1 - mx);
        float e2 = (ck == 3) ? __expf(v2 - mx) : 0.0f;
        float inv = 1.0f / (e0 + e1 + e2);
        size_t basek = (b < 5) ? (size_t)b * 3 * N + (size_t)i * 3
                               : (size_t)15 * N + (size_t)(b - 5) * 2 * N + (size_t)i * 2;
        out[basek + 0] = e0 * inv;
        out[basek + 1] = e1 * inv;
        if (ck == 3) out[basek + 2] = e2 * inv;
    }
}

// ---- launch -------------------------------------------------------------
extern "C" void kernel_launch(void* const* d_in, const int* in_sizes, int n_in,
                              void* d_out, int out_size, void* d_ws, size_t ws_size,
                              hipStream_t stream) {
    (void)n_in; (void)out_size; (void)ws_size;
    const float* x   = (const float*)d_in[0];
    const int*   ei  = (const int*)d_in[1];
    const float* gw  = (const float*)d_in[2];
    const float* gb  = (const float*)d_in[3];
    const float* r3w = (const float*)d_in[4];
    const float* r3b = (const float*)d_in[5];
    const float* r2w = (const float*)d_in[6];
    const float* r2b = (const float*)d_in[7];
    float* out = (float*)d_out;
    int N = in_sizes[0] / H;   // 100000
    int E = in_sizes[1] / 2;   // 1600000
    int NB = (N + 255) >> 8;   // 391 buckets

    char* p = (char*)d_ws;
    auto alloc = [&](size_t bytes) {
        char* q = p;
        p += (bytes + 255) & ~(size_t)255;
        return q;
    };
    unsigned*       xb     = (unsigned*)alloc((size_t)N * 64 * 4);
    unsigned*       pxb    = (unsigned*)alloc((size_t)N * 64 * 4);
    unsigned short* Wt     = (unsigned short*)alloc((size_t)7 * 16384 * 2);
    unsigned short* WRb    = (unsigned short*)alloc((size_t)14336 * 2);
    float*          bias2  = (float*)alloc(32 * 4);
    int*            bhist  = (int*)alloc(512 * 4);
    int*            bbase  = (int*)alloc(513 * 4);
    int*            gcur   = (int*)alloc(512 * 4);
    int2*           tmp_sd = (int2*)alloc((size_t)E * 8);
    int*            rp     = (int*)alloc((size_t)(N + 1) * 4);
    float*          dinv   = (float*)alloc((size_t)N * 4);
    float*          invdeg = (float*)alloc((size_t)N * 4);
    int*            csrc   = (int*)alloc((size_t)E * 4);
    float*          cw     = (float*)alloc((size_t)E * 4);
    float*          uall   = (float*)alloc((size_t)N * 32 * 4);

    hipMemsetAsync(bhist, 0, 512 * 4, stream);
    k_bhist<<<256, 256, 0, stream>>>(ei, bhist, E);
    k_bscan<<<1, 512, 0, stream>>>(bhist, bbase, gcur);
    k_scatter<<<256, 256, 0, stream>>>(ei, gcur, tmp_sd, E);
    k_csrA<<<NB, 256, 0, stream>>>(tmp_sd, bbase, rp, dinv, invdeg, N, E);
    k_csrB<<<NB, 256, 0, stream>>>(tmp_sd, bbase, rp, dinv, csrc, cw, N);
    k_xbf<<<(N * 64 + 255) / 256, 256, 0, stream>>>(x, xb, N * 64);
    k_wprep<<<(114688 + 14368 + 255) / 256, 256, 0, stream>>>(gw, gb, r3w, r3b, r2w, r2b,
                                                              Wt, WRb, bias2);
    k_px<<<(N + 3) / 4, 256, 0, stream>>>(xb, rp, csrc, cw, invdeg, pxb, N);
    dim3 gg((N + 511) / 512, 7);
    k_gemm<<<gg, 256, 0, stream>>>((const unsigned short*)pxb, Wt, gb, WRb, uall, N);
    k_out<<<(N + 3) / 4, 256, 0, stream>>>(uall, rp, csrc, cw, invdeg, bias2, out, N);
}